// Round 18
// baseline (39.781 us; speedup 1.0000x reference)
//
#include <hip/hip_runtime.h>

#define HW 16384
#define CIN 64
#define COUT 64
#define HH 128
#define WW 128
#define NB 4
#define PXB 32
#define TPB 2

typedef __attribute__((ext_vector_type(8))) short bf16x8;
typedef __attribute__((ext_vector_type(4))) float f32x4;
typedef __attribute__((ext_vector_type(8))) unsigned short u16x8;

__device__ __forceinline__ unsigned short f32_bf16(float f) {
  unsigned u = __builtin_bit_cast(unsigned, f);
  u += 0x7fffu + ((u >> 16) & 1u);
  return (unsigned short)(u >> 16);
}
__device__ __forceinline__ float bits_f32(unsigned u) {
  return __builtin_bit_cast(float, u);
}

// raw barrier: drain LDS ops only (NOT vmcnt -- keeps gathers in flight)
#define SYNCB()                                              \
  do {                                                       \
    asm volatile("s_waitcnt lgkmcnt(0)" ::: "memory");       \
    __builtin_amdgcn_s_barrier();                            \
    __builtin_amdgcn_sched_barrier(0);                       \
  } while (0)

// ---- fused prep: blocks [0,1024) transpose x; [1024,1168) transpose w ----
__global__ __launch_bounds__(256) void prep_kernel(
    const float* __restrict__ x, const float* __restrict__ w,
    unsigned short* __restrict__ xt, unsigned short* __restrict__ wt) {
  __shared__ float tile[64][65];
  const int bid = blockIdx.x;
  if (bid < 1024) {
    const int n = bid >> 8;
    const int hw0 = (bid & 255) * 64;
    const int tx = threadIdx.x & 63;
    const int ty = threadIdx.x >> 6;
    const float* xp = x + (size_t)n * CIN * HW;
    #pragma unroll
    for (int c = ty; c < 64; c += 4)
      tile[c][tx] = xp[(size_t)c * HW + hw0 + tx];
    __syncthreads();
    unsigned short* xtp = xt + (size_t)n * HW * CIN;
    #pragma unroll
    for (int hw = ty; hw < 64; hw += 4)
      xtp[(size_t)(hw0 + hw) * CIN + tx] = f32_bf16(tile[tx][hw]);
  } else {
    const int i = (bid - 1024) * 256 + threadIdx.x;
    if (i < 64 * 576) {
      const int o = i / 576;
      const int t = i % 576;          // t = k*64 + c
      const int c = t & 63;
      const int k = t >> 6;
      wt[i] = f32_bf16(w[((size_t)o * 64 + c) * 9 + k]);
    }
  }
}

// ---- main: 16B-lane gathers, tap-pipelined blend (distance 3), MFMA(t-1)
// under the first taps' latency. TPB=2 x PXB=32 px (64 px/block); grid 1024
// -> 3 blocks/CU (LDS 43.7KB) = 3 waves/SIMD at launch_bounds (256,3)
// (VGPR cap ~170; est. need ~150-165: bv 72 + V 48 + temps).
__global__ __launch_bounds__(256, 3) void deform_mfma(
    const unsigned short* __restrict__ xt, const float* __restrict__ offset,
    const unsigned short* __restrict__ wt, float* __restrict__ out) {
  __shared__ unsigned short s[PXB][584];   // 37.4 KB sampled tile
  __shared__ f32x4 pw[288];                // bilinear weights per (tap,px)
  __shared__ uint2 pidx[288];              // packed corner indices
  const int tid = threadIdx.x;
  const int wave = tid >> 6;
  const int lane = tid & 63;
  const int g16 = lane >> 4;               // MFMA k-group
  const int li16 = lane & 15;              // MFMA row
  const int px = wave * 8 + (lane >> 3);   // gather pixel (8-lane groups)
  const int li8 = lane & 7;                // gather lane: ch li8*8..+7
  const int base = blockIdx.x * (PXB * TPB);
  const int n = base >> 14;                // 64 px/block, no n straddle
  const int rem_base = base & 16383;

  const float* offb = offset + (size_t)n * 18 * HW;
  const unsigned short* xli = xt + (size_t)n * HW * CIN + li8 * 8;

  const int px0 = tid & 31;                // params: item0 = (tap tid>>5, px0)
  const int tap0 = tid >> 5;               // taps 0..7; item1 = tap 8, tid<32

  // B-fragments: tile-invariant, preload once (18 x 4 VGPR, held).
  bf16x8 bv[18];
  {
    const unsigned short* bp = wt + ((size_t)(wave * 16 + li16)) * 576 + g16 * 8;
    #pragma unroll
    for (int i = 0; i < 18; ++i)
      bv[i] = *(const bf16x8*)(bp + i * 32);
  }

  #define PARAMS(tt, tapv, dyv, dxv)                                       \
    do {                                                                   \
      const int rem = rem_base + (tt) * PXB + px0;                         \
      const int y = rem >> 7;                                              \
      const int x = rem & 127;                                             \
      const float fy = floorf(dyv);                                        \
      const float fx = floorf(dxv);                                        \
      const float ly = (dyv)-fy;                                           \
      const float lx = (dxv)-fx;                                           \
      const int y0 = y - 1 + ((tapv) / 3) + (int)fy;                       \
      const int x0 = x - 1 + ((tapv) % 3) + (int)fx;                       \
      const int y1 = y0 + 1, x1 = x0 + 1;                                  \
      const bool vy0 = (unsigned)y0 < (unsigned)HH;                        \
      const bool vy1 = (unsigned)y1 < (unsigned)HH;                        \
      const bool vx0 = (unsigned)x0 < (unsigned)WW;                        \
      const bool vx1 = (unsigned)x1 < (unsigned)WW;                        \
      const int cy0 = min(max(y0, 0), HH - 1);                             \
      const int cy1 = min(max(y1, 0), HH - 1);                             \
      const int cx0 = min(max(x0, 0), WW - 1);                             \
      const int cx1 = min(max(x1, 0), WW - 1);                             \
      const float omly = 1.f - ly, omlx = 1.f - lx;                        \
      f32x4 w4;                                                            \
      w4[0] = (vy0 && vx0) ? omly * omlx : 0.f;                            \
      w4[1] = (vy0 && vx1) ? omly * lx : 0.f;                              \
      w4[2] = (vy1 && vx0) ? ly * omlx : 0.f;                              \
      w4[3] = (vy1 && vx1) ? ly * lx : 0.f;                                \
      const unsigned i00 = (unsigned)(cy0 * WW + cx0);                     \
      const unsigned i01 = (unsigned)(cy0 * WW + cx1);                     \
      const unsigned i10 = (unsigned)(cy1 * WW + cx0);                     \
      const unsigned i11 = (unsigned)(cy1 * WW + cx1);                     \
      pw[(tapv)*32 + px0] = w4;                                            \
      pidx[(tapv)*32 + px0] = make_uint2(i00 | (i01 << 16), i10 | (i11 << 16)); \
    } while (0)

  u16x8 V[3][4];   // [slot][corner], 16B each -> 48 VGPR

  #define ISSUE(kk, sl)                                                    \
    do {                                                                   \
      const uint2 id = pidx[(kk)*32 + px];                                 \
      V[sl][0] = *(const u16x8*)(xli + (size_t)(id.x & 0xffffu) * CIN);    \
      V[sl][1] = *(const u16x8*)(xli + (size_t)(id.x >> 16) * CIN);        \
      V[sl][2] = *(const u16x8*)(xli + (size_t)(id.y & 0xffffu) * CIN);    \
      V[sl][3] = *(const u16x8*)(xli + (size_t)(id.y >> 16) * CIN);        \
    } while (0)

  #define BLEND(kk, sl)                                                    \
    do {                                                                   \
      const f32x4 w = pw[(kk)*32 + px];                                    \
      float a[8] = {0.f, 0.f, 0.f, 0.f, 0.f, 0.f, 0.f, 0.f};               \
      _Pragma("unroll")                                                    \
      for (int c = 0; c < 4; ++c) {                                        \
        _Pragma("unroll")                                                  \
        for (int j = 0; j < 8; ++j)                                        \
          a[j] = fmaf(bits_f32((unsigned)V[sl][c][j] << 16), w[c], a[j]);  \
      }                                                                    \
      unsigned r0, r1, r2, r3;                                             \
      asm("v_cvt_pk_bf16_f32 %0, %1, %2" : "=v"(r0) : "v"(a[0]), "v"(a[1])); \
      asm("v_cvt_pk_bf16_f32 %0, %1, %2" : "=v"(r1) : "v"(a[2]), "v"(a[3])); \
      asm("v_cvt_pk_bf16_f32 %0, %1, %2" : "=v"(r2) : "v"(a[4]), "v"(a[5])); \
      asm("v_cvt_pk_bf16_f32 %0, %1, %2" : "=v"(r3) : "v"(a[6]), "v"(a[7])); \
      *(uint4*)&s[px][(kk)*64 + li8 * 8] = make_uint4(r0, r1, r2, r3);     \
    } while (0)

  #define MFMA_OUT(remt)                                                   \
    do {                                                                   \
      f32x4 acc0 = {0.f, 0.f, 0.f, 0.f};                                   \
      f32x4 acc1 = {0.f, 0.f, 0.f, 0.f};                                   \
      const unsigned short* ap0 = &s[li16][g16 * 8];                       \
      const unsigned short* ap1 = &s[16 + li16][g16 * 8];                  \
      _Pragma("unroll")                                                    \
      for (int i = 0; i < 18; ++i) {                                       \
        bf16x8 a0 = *(const bf16x8*)(ap0 + i * 32);                        \
        bf16x8 a1 = *(const bf16x8*)(ap1 + i * 32);                        \
        acc0 = __builtin_amdgcn_mfma_f32_16x16x32_bf16(a0, bv[i], acc0, 0, 0, 0); \
        acc1 = __builtin_amdgcn_mfma_f32_16x16x32_bf16(a1, bv[i], acc1, 0, 0, 0); \
      }                                                                    \
      const int oc = wave * 16 + li16;                                     \
      float* ob = out + ((size_t)n * COUT + oc) * HW + (remt) + g16 * 4;   \
      *(f32x4*)ob = acc0;                                                  \
      *(f32x4*)(ob + 16) = acc1;                                           \
    } while (0)

  // ---- prologue: load offsets(0) ----
  float dy0, dx0, dy1 = 0.f, dx1 = 0.f;
  {
    const int rem = rem_base + px0;
    dy0 = offb[(size_t)(2 * tap0) * HW + rem];
    dx0 = offb[(size_t)(2 * tap0 + 1) * HW + rem];
    if (tid < 32) {
      dy1 = offb[(size_t)16 * HW + rem];
      dx1 = offb[(size_t)17 * HW + rem];
    }
  }

  int prev_rem0 = 0;

  #pragma unroll 1
  for (int t = 0; t < TPB; ++t) {
    const int rem0 = rem_base + t * PXB;

    // A: params(t)
    PARAMS(t, tap0, dy0, dx0);
    if (tid < 32) PARAMS(t, 8, dy1, dx1);
    SYNCB();   // BAR_a: params(t) visible

    // C: prefetch offsets(t+1)
    if (t + 1 < TPB) {
      const int rem = rem_base + (t + 1) * PXB + px0;
      dy0 = offb[(size_t)(2 * tap0) * HW + rem];
      dx0 = offb[(size_t)(2 * tap0 + 1) * HW + rem];
      if (tid < 32) {
        dy1 = offb[(size_t)16 * HW + rem];
        dx1 = offb[(size_t)17 * HW + rem];
      }
    }

    // D: issue taps 0..2
    ISSUE(0, 0);
    ISSUE(1, 1);
    ISSUE(2, 2);
    __builtin_amdgcn_sched_barrier(0);

    // M: MFMA(t-1) -- pure LDS+reg+store, covers taps 0..2 latency
    if (t > 0) MFMA_OUT(prev_rem0);
    SYNCB();   // BAR_b: M's s-reads done before E overwrites

    // E: tap-pipelined blend (distance 3)
    BLEND(0, 0); ISSUE(3, 0);
    BLEND(1, 1); ISSUE(4, 1);
    BLEND(2, 2); ISSUE(5, 2);
    BLEND(3, 0); ISSUE(6, 0);
    BLEND(4, 1); ISSUE(7, 1);
    BLEND(5, 2); ISSUE(8, 2);
    BLEND(6, 0);
    BLEND(7, 1);
    BLEND(8, 2);
    SYNCB();   // BAR_c: s(t) visible; params bank free for A(t+1)

    prev_rem0 = rem0;
  }

  // epilogue: MFMA(TPB-1)
  MFMA_OUT(prev_rem0);

  #undef PARAMS
  #undef ISSUE
  #undef BLEND
  #undef MFMA_OUT
}

// ---------------- fp32 fallback (ws too small) --------------------------
__global__ __launch_bounds__(256) void deform_fallback(
    const float* __restrict__ xsrc, const float* __restrict__ offset,
    const float* __restrict__ wsrc, float* __restrict__ out) {
  __shared__ float s[16][576];
  const int wave = threadIdx.x >> 6;
  const int lane = threadIdx.x & 63;
  const int p0 = blockIdx.x * 16;
  for (int i = 0; i < 4; ++i) {
    const int p = p0 + wave * 4 + i;
    const int n = p >> 14;
    const int rem = p & 16383;
    const int y = rem >> 7;
    const int x = rem & 127;
    const float* off = offset + (size_t)n * 18 * HW + rem;
    const float* xb = xsrc + (size_t)n * CIN * HW;
    #pragma unroll
    for (int k = 0; k < 9; ++k) {
      const float dy = off[(size_t)(2 * k) * HW];
      const float dx = off[(size_t)(2 * k + 1) * HW];
      const float py = (float)(y - 1 + k / 3) + dy;
      const float px = (float)(x - 1 + k % 3) + dx;
      const float y0f = floorf(py), x0f = floorf(px);
      const float ly = py - y0f, lx = px - x0f;
      const int y0 = (int)y0f, x0 = (int)x0f;
      const int y1 = y0 + 1, x1 = x0 + 1;
      const bool vy0 = (y0 >= 0) && (y0 < HH), vy1 = (y1 >= 0) && (y1 < HH);
      const bool vx0 = (x0 >= 0) && (x0 < WW), vx1 = (x1 >= 0) && (x1 < WW);
      const int cy0 = min(max(y0, 0), HH - 1), cy1 = min(max(y1, 0), HH - 1);
      const int cx0 = min(max(x0, 0), WW - 1), cx1 = min(max(x1, 0), WW - 1);
      const float v00 = (vy0 && vx0) ? xb[(size_t)lane * HW + cy0 * WW + cx0] : 0.f;
      const float v01 = (vy0 && vx1) ? xb[(size_t)lane * HW + cy0 * WW + cx1] : 0.f;
      const float v10 = (vy1 && vx0) ? xb[(size_t)lane * HW + cy1 * WW + cx0] : 0.f;
      const float v11 = (vy1 && vx1) ? xb[(size_t)lane * HW + cy1 * WW + cx1] : 0.f;
      s[wave * 4 + i][k * 64 + lane] =
          v00 * (1.f - ly) * (1.f - lx) + v01 * (1.f - ly) * lx +
          v10 * ly * (1.f - lx) + v11 * ly * lx;
    }
  }
  __syncthreads();
  float a0 = 0.f, a1 = 0.f, a2 = 0.f, a3 = 0.f;
  const int pb = wave * 4;
  for (int t = 0; t < 576; ++t) {
    const int c = t & 63;
    const int k = t >> 6;
    const float wv = wsrc[((size_t)lane * 64 + c) * 9 + k];
    a0 += s[pb + 0][t] * wv;
    a1 += s[pb + 1][t] * wv;
    a2 += s[pb + 2][t] * wv;
    a3 += s[pb + 3][t] * wv;
  }
  const float acc[4] = {a0, a1, a2, a3};
  for (int i = 0; i < 4; ++i) {
    const int p = p0 + pb + i;
    const int n = p >> 14;
    const int rem = p & 16383;
    out[((size_t)n * COUT + lane) * HW + rem] = acc[i];
  }
}

extern "C" void kernel_launch(void* const* d_in, const int* in_sizes, int n_in,
                              void* d_out, int out_size, void* d_ws,
                              size_t ws_size, hipStream_t stream) {
  const float* x = (const float*)d_in[0];
  const float* offset = (const float*)d_in[1];
  const float* weight = (const float*)d_in[2];
  float* out = (float*)d_out;

  const size_t xt_elems = (size_t)NB * HW * CIN;       // bf16
  const size_t wt_elems = (size_t)64 * 576;            // bf16
  const size_t need = (xt_elems + wt_elems) * sizeof(short);

  if (ws_size >= need) {
    unsigned short* xtp = (unsigned short*)d_ws;
    unsigned short* wtp = xtp + xt_elems;
    prep_kernel<<<1024 + 144, 256, 0, stream>>>(x, weight, xtp, wtp);
    deform_mfma<<<NB * HW / (PXB * TPB), 256, 0, stream>>>(xtp, offset, wtp, out);
  } else {
    deform_fallback<<<NB * HW / 16, 256, 0, stream>>>(x, offset, weight, out);
  }
}

// Round 19
// 36.069 us; speedup vs baseline: 1.1029x; 1.1029x over previous
//
#include <hip/hip_runtime.h>

#define HW 16384
#define CIN 64
#define COUT 64
#define HH 128
#define WW 128
#define NB 4
#define PXB 32
#define TPB 4

typedef __attribute__((ext_vector_type(8))) short bf16x8;
typedef __attribute__((ext_vector_type(4))) float f32x4;
typedef __attribute__((ext_vector_type(8))) unsigned short u16x8;

__device__ __forceinline__ unsigned short f32_bf16(float f) {
  unsigned u = __builtin_bit_cast(unsigned, f);
  u += 0x7fffu + ((u >> 16) & 1u);
  return (unsigned short)(u >> 16);
}
__device__ __forceinline__ float bits_f32(unsigned u) {
  return __builtin_bit_cast(float, u);
}

// raw barrier: drain LDS ops only (NOT vmcnt -- keeps gathers in flight)
#define SYNCB()                                              \
  do {                                                       \
    asm volatile("s_waitcnt lgkmcnt(0)" ::: "memory");       \
    __builtin_amdgcn_s_barrier();                            \
    __builtin_amdgcn_sched_barrier(0);                       \
  } while (0)

// ---- fused prep: blocks [0,1024) transpose x; [1024,1168) transpose w ----
__global__ __launch_bounds__(256) void prep_kernel(
    const float* __restrict__ x, const float* __restrict__ w,
    unsigned short* __restrict__ xt, unsigned short* __restrict__ wt) {
  __shared__ float tile[64][65];
  const int bid = blockIdx.x;
  if (bid < 1024) {
    const int n = bid >> 8;
    const int hw0 = (bid & 255) * 64;
    const int tx = threadIdx.x & 63;
    const int ty = threadIdx.x >> 6;
    const float* xp = x + (size_t)n * CIN * HW;
    #pragma unroll
    for (int c = ty; c < 64; c += 4)
      tile[c][tx] = xp[(size_t)c * HW + hw0 + tx];
    __syncthreads();
    unsigned short* xtp = xt + (size_t)n * HW * CIN;
    #pragma unroll
    for (int hw = ty; hw < 64; hw += 4)
      xtp[(size_t)(hw0 + hw) * CIN + tx] = f32_bf16(tile[tx][hw]);
  } else {
    const int i = (bid - 1024) * 256 + threadIdx.x;
    if (i < 64 * 576) {
      const int o = i / 576;
      const int t = i % 576;          // t = k*64 + c
      const int c = t & 63;
      const int k = t >> 6;
      wt[i] = f32_bf16(w[((size_t)o * 64 + c) * 9 + k]);
    }
  }
}

// ---- main (R17 structure, 2 barriers/tile, distance-4 tap pipeline) ----
// block = 256 thr = 4 waves; TPB=4 tiles of PXB=32 px (128 px/block);
// grid 512, 2 blocks/CU at (256,2). Per tile:
//   C: prefetch offsets(t+1) regs;
//   D: issue taps 0..3 (V slots 0..3, bank t&1);
//   M: MFMA(t-1) -- pure LDS+reg+store (bv preloaded: no vmcnt drain);
//   BAR_b (lgkm only);
//   E: BLEND(k)/ISSUE(k+4) interleave k=0..8 -> s(t); PARAMS(t+1)->bank
//      (t+1)&1 at tail (offsets prefetched a full tile earlier);
//   BAR_c: publishes s(t) AND params(t+1).
__global__ __launch_bounds__(256, 2) void deform_mfma(
    const unsigned short* __restrict__ xt, const float* __restrict__ offset,
    const unsigned short* __restrict__ wt, float* __restrict__ out) {
  __shared__ unsigned short s[PXB][584];   // 37.4 KB sampled tile
  __shared__ f32x4 pw[2][288];             // bilinear weights, dbuf
  __shared__ uint2 pidx[2][288];           // packed corner indices, dbuf
  const int tid = threadIdx.x;
  const int wave = tid >> 6;
  const int lane = tid & 63;
  const int g16 = lane >> 4;               // MFMA k-group
  const int li16 = lane & 15;              // MFMA row
  const int px = wave * 8 + (lane >> 3);   // gather pixel (8-lane groups)
  const int li8 = lane & 7;                // gather lane: ch li8*8..+7
  const int base = blockIdx.x * (PXB * TPB);
  const int n = base >> 14;                // 128 px/block, no n straddle
  const int rem_base = base & 16383;

  const float* offb = offset + (size_t)n * 18 * HW;
  const unsigned short* xli = xt + (size_t)n * HW * CIN + li8 * 8;

  const int px0 = tid & 31;                // params: item0 = (tap tid>>5, px0)
  const int tap0 = tid >> 5;               // taps 0..7; item1 = tap 8, tid<32

  // B-fragments: tile-invariant, preload once (18 x 4 VGPR, held).
  bf16x8 bv[18];
  {
    const unsigned short* bp = wt + ((size_t)(wave * 16 + li16)) * 576 + g16 * 8;
    #pragma unroll
    for (int i = 0; i < 18; ++i)
      bv[i] = *(const bf16x8*)(bp + i * 32);
  }

  #define PARAMS(tt, wb, tapv, dyv, dxv)                                   \
    do {                                                                   \
      const int rem = rem_base + (tt) * PXB + px0;                         \
      const int y = rem >> 7;                                              \
      const int x = rem & 127;                                             \
      const float fy = floorf(dyv);                                        \
      const float fx = floorf(dxv);                                        \
      const float ly = (dyv)-fy;                                           \
      const float lx = (dxv)-fx;                                           \
      const int y0 = y - 1 + ((tapv) / 3) + (int)fy;                       \
      const int x0 = x - 1 + ((tapv) % 3) + (int)fx;                       \
      const int y1 = y0 + 1, x1 = x0 + 1;                                  \
      const bool vy0 = (unsigned)y0 < (unsigned)HH;                        \
      const bool vy1 = (unsigned)y1 < (unsigned)HH;                        \
      const bool vx0 = (unsigned)x0 < (unsigned)WW;                        \
      const bool vx1 = (unsigned)x1 < (unsigned)WW;                        \
      const int cy0 = min(max(y0, 0), HH - 1);                             \
      const int cy1 = min(max(y1, 0), HH - 1);                             \
      const int cx0 = min(max(x0, 0), WW - 1);                             \
      const int cx1 = min(max(x1, 0), WW - 1);                             \
      const float omly = 1.f - ly, omlx = 1.f - lx;                        \
      f32x4 w4;                                                            \
      w4[0] = (vy0 && vx0) ? omly * omlx : 0.f;                            \
      w4[1] = (vy0 && vx1) ? omly * lx : 0.f;                              \
      w4[2] = (vy1 && vx0) ? ly * omlx : 0.f;                              \
      w4[3] = (vy1 && vx1) ? ly * lx : 0.f;                                \
      const unsigned i00 = (unsigned)(cy0 * WW + cx0);                     \
      const unsigned i01 = (unsigned)(cy0 * WW + cx1);                     \
      const unsigned i10 = (unsigned)(cy1 * WW + cx0);                     \
      const unsigned i11 = (unsigned)(cy1 * WW + cx1);                     \
      pw[wb][(tapv)*32 + px0] = w4;                                        \
      pidx[wb][(tapv)*32 + px0] =                                          \
          make_uint2(i00 | (i01 << 16), i10 | (i11 << 16));                \
    } while (0)

  u16x8 V[4][4];   // [slot][corner], 16B each -> 64 VGPR

  #define ISSUE(kk, sl, rb)                                                \
    do {                                                                   \
      const uint2 id = pidx[rb][(kk)*32 + px];                             \
      V[sl][0] = *(const u16x8*)(xli + (size_t)(id.x & 0xffffu) * CIN);    \
      V[sl][1] = *(const u16x8*)(xli + (size_t)(id.x >> 16) * CIN);        \
      V[sl][2] = *(const u16x8*)(xli + (size_t)(id.y & 0xffffu) * CIN);    \
      V[sl][3] = *(const u16x8*)(xli + (size_t)(id.y >> 16) * CIN);        \
    } while (0)

  #define BLEND(kk, sl, rb)                                                \
    do {                                                                   \
      const f32x4 w = pw[rb][(kk)*32 + px];                                \
      float a[8] = {0.f, 0.f, 0.f, 0.f, 0.f, 0.f, 0.f, 0.f};               \
      _Pragma("unroll")                                                    \
      for (int c = 0; c < 4; ++c) {                                        \
        _Pragma("unroll")                                                  \
        for (int j = 0; j < 8; ++j)                                        \
          a[j] = fmaf(bits_f32((unsigned)V[sl][c][j] << 16), w[c], a[j]);  \
      }                                                                    \
      unsigned r0, r1, r2, r3;                                             \
      asm("v_cvt_pk_bf16_f32 %0, %1, %2" : "=v"(r0) : "v"(a[0]), "v"(a[1])); \
      asm("v_cvt_pk_bf16_f32 %0, %1, %2" : "=v"(r1) : "v"(a[2]), "v"(a[3])); \
      asm("v_cvt_pk_bf16_f32 %0, %1, %2" : "=v"(r2) : "v"(a[4]), "v"(a[5])); \
      asm("v_cvt_pk_bf16_f32 %0, %1, %2" : "=v"(r3) : "v"(a[6]), "v"(a[7])); \
      *(uint4*)&s[px][(kk)*64 + li8 * 8] = make_uint4(r0, r1, r2, r3);     \
    } while (0)

  #define MFMA_OUT(remt)                                                   \
    do {                                                                   \
      f32x4 acc0 = {0.f, 0.f, 0.f, 0.f};                                   \
      f32x4 acc1 = {0.f, 0.f, 0.f, 0.f};                                   \
      const unsigned short* ap0 = &s[li16][g16 * 8];                       \
      const unsigned short* ap1 = &s[16 + li16][g16 * 8];                  \
      _Pragma("unroll")                                                    \
      for (int i = 0; i < 18; ++i) {                                       \
        bf16x8 a0 = *(const bf16x8*)(ap0 + i * 32);                        \
        bf16x8 a1 = *(const bf16x8*)(ap1 + i * 32);                        \
        acc0 = __builtin_amdgcn_mfma_f32_16x16x32_bf16(a0, bv[i], acc0, 0, 0, 0); \
        acc1 = __builtin_amdgcn_mfma_f32_16x16x32_bf16(a1, bv[i], acc1, 0, 0, 0); \
      }                                                                    \
      const int oc = wave * 16 + li16;                                     \
      float* ob = out + ((size_t)n * COUT + oc) * HW + (remt) + g16 * 4;   \
      *(f32x4*)ob = acc0;                                                  \
      *(f32x4*)(ob + 16) = acc1;                                           \
    } while (0)

  // ---- prologue: offsets(0) -> params(0) -> barrier ----
  float dy0, dx0, dy1 = 0.f, dx1 = 0.f;
  {
    const int rem = rem_base + px0;
    dy0 = offb[(size_t)(2 * tap0) * HW + rem];
    dx0 = offb[(size_t)(2 * tap0 + 1) * HW + rem];
    if (tid < 32) {
      dy1 = offb[(size_t)16 * HW + rem];
      dx1 = offb[(size_t)17 * HW + rem];
    }
  }
  PARAMS(0, 0, tap0, dy0, dx0);
  if (tid < 32) PARAMS(0, 0, 8, dy1, dx1);
  SYNCB();   // params(0) visible

  int prev_rem0 = 0;

  #pragma unroll 1
  for (int t = 0; t < TPB; ++t) {
    const int rem0 = rem_base + t * PXB;
    const int rb = t & 1;

    // C: prefetch offsets(t+1) -- consumed by PARAMS at tail of E
    if (t + 1 < TPB) {
      const int rem = rem_base + (t + 1) * PXB + px0;
      dy0 = offb[(size_t)(2 * tap0) * HW + rem];
      dx0 = offb[(size_t)(2 * tap0 + 1) * HW + rem];
      if (tid < 32) {
        dy1 = offb[(size_t)16 * HW + rem];
        dx1 = offb[(size_t)17 * HW + rem];
      }
    }

    // D: issue taps 0..3
    ISSUE(0, 0, rb);
    ISSUE(1, 1, rb);
    ISSUE(2, 2, rb);
    ISSUE(3, 3, rb);
    __builtin_amdgcn_sched_barrier(0);

    // M: MFMA(t-1) -- pure LDS+reg+store, covers taps 0..3 latency
    if (t > 0) MFMA_OUT(prev_rem0);
    SYNCB();   // BAR_b: M's s-reads done before E overwrites

    // E: tap-pipelined blend (distance 4) + params(t+1) at tail
    BLEND(0, 0, rb); ISSUE(4, 0, rb);
    BLEND(1, 1, rb); ISSUE(5, 1, rb);
    BLEND(2, 2, rb); ISSUE(6, 2, rb);
    BLEND(3, 3, rb); ISSUE(7, 3, rb);
    BLEND(4, 0, rb); ISSUE(8, 0, rb);
    BLEND(5, 1, rb);
    BLEND(6, 2, rb);
    BLEND(7, 3, rb);
    BLEND(8, 0, rb);
    if (t + 1 < TPB) {
      PARAMS(t + 1, (t + 1) & 1, tap0, dy0, dx0);
      if (tid < 32) PARAMS(t + 1, (t + 1) & 1, 8, dy1, dx1);
    }
    SYNCB();   // BAR_c: s(t) + params(t+1) visible

    prev_rem0 = rem0;
  }

  // epilogue: MFMA(TPB-1)
  MFMA_OUT(prev_rem0);

  #undef PARAMS
  #undef ISSUE
  #undef BLEND
  #undef MFMA_OUT
}

// ---------------- fp32 fallback (ws too small) --------------------------
__global__ __launch_bounds__(256) void deform_fallback(
    const float* __restrict__ xsrc, const float* __restrict__ offset,
    const float* __restrict__ wsrc, float* __restrict__ out) {
  __shared__ float s[16][576];
  const int wave = threadIdx.x >> 6;
  const int lane = threadIdx.x & 63;
  const int p0 = blockIdx.x * 16;
  for (int i = 0; i < 4; ++i) {
    const int p = p0 + wave * 4 + i;
    const int n = p >> 14;
    const int rem = p & 16383;
    const int y = rem >> 7;
    const int x = rem & 127;
    const float* off = offset + (size_t)n * 18 * HW + rem;
    const float* xb = xsrc + (size_t)n * CIN * HW;
    #pragma unroll
    for (int k = 0; k < 9; ++k) {
      const float dy = off[(size_t)(2 * k) * HW];
      const float dx = off[(size_t)(2 * k + 1) * HW];
      const float py = (float)(y - 1 + k / 3) + dy;
      const float px = (float)(x - 1 + k % 3) + dx;
      const float y0f = floorf(py), x0f = floorf(px);
      const float ly = py - y0f, lx = px - x0f;
      const int y0 = (int)y0f, x0 = (int)x0f;
      const int y1 = y0 + 1, x1 = x0 + 1;
      const bool vy0 = (y0 >= 0) && (y0 < HH), vy1 = (y1 >= 0) && (y1 < HH);
      const bool vx0 = (x0 >= 0) && (x0 < WW), vx1 = (x1 >= 0) && (x1 < WW);
      const int cy0 = min(max(y0, 0), HH - 1), cy1 = min(max(y1, 0), HH - 1);
      const int cx0 = min(max(x0, 0), WW - 1), cx1 = min(max(x1, 0), WW - 1);
      const float v00 = (vy0 && vx0) ? xb[(size_t)lane * HW + cy0 * WW + cx0] : 0.f;
      const float v01 = (vy0 && vx1) ? xb[(size_t)lane * HW + cy0 * WW + cx1] : 0.f;
      const float v10 = (vy1 && vx0) ? xb[(size_t)lane * HW + cy1 * WW + cx0] : 0.f;
      const float v11 = (vy1 && vx1) ? xb[(size_t)lane * HW + cy1 * WW + cx1] : 0.f;
      s[wave * 4 + i][k * 64 + lane] =
          v00 * (1.f - ly) * (1.f - lx) + v01 * (1.f - ly) * lx +
          v10 * ly * (1.f - lx) + v11 * ly * lx;
    }
  }
  __syncthreads();
  float a0 = 0.f, a1 = 0.f, a2 = 0.f, a3 = 0.f;
  const int pb = wave * 4;
  for (int t = 0; t < 576; ++t) {
    const int c = t & 63;
    const int k = t >> 6;
    const float wv = wsrc[((size_t)lane * 64 + c) * 9 + k];
    a0 += s[pb + 0][t] * wv;
    a1 += s[pb + 1][t] * wv;
    a2 += s[pb + 2][t] * wv;
    a3 += s[pb + 3][t] * wv;
  }
  const float acc[4] = {a0, a1, a2, a3};
  for (int i = 0; i < 4; ++i) {
    const int p = p0 + pb + i;
    const int n = p >> 14;
    const int rem = p & 16383;
    out[((size_t)n * COUT + lane) * HW + rem] = acc[i];
  }
}

extern "C" void kernel_launch(void* const* d_in, const int* in_sizes, int n_in,
                              void* d_out, int out_size, void* d_ws,
                              size_t ws_size, hipStream_t stream) {
  const float* x = (const float*)d_in[0];
  const float* offset = (const float*)d_in[1];
  const float* weight = (const float*)d_in[2];
  float* out = (float*)d_out;

  const size_t xt_elems = (size_t)NB * HW * CIN;       // bf16
  const size_t wt_elems = (size_t)64 * 576;            // bf16
  const size_t need = (xt_elems + wt_elems) * sizeof(short);

  if (ws_size >= need) {
    unsigned short* xtp = (unsigned short*)d_ws;
    unsigned short* wtp = xtp + xt_elems;
    prep_kernel<<<1024 + 144, 256, 0, stream>>>(x, weight, xtp, wtp);
    deform_mfma<<<NB * HW / (PXB * TPB), 256, 0, stream>>>(xtp, offset, wtp, out);
  } else {
    deform_fallback<<<NB * HW / 16, 256, 0, stream>>>(x, offset, weight, out);
  }
}